// Round 1
// baseline (489.748 us; speedup 1.0000x reference)
//
#include <hip/hip_runtime.h>

#define S_LEN 2048
#define D_DIM 1024
#define NH 16
#define HD 64
#define BATCH 2

using s16x8 = __attribute__((ext_vector_type(8))) short;
using u16x8 = __attribute__((ext_vector_type(8))) unsigned short;
using f32x4 = __attribute__((ext_vector_type(4))) float;
using bf16x8v = __attribute__((ext_vector_type(8))) __bf16;

__device__ __forceinline__ unsigned short f32_to_bf16(float f) {
  unsigned int u = __float_as_uint(f);
  u += 0x7FFFu + ((u >> 16) & 1u);
  return (unsigned short)(u >> 16);
}

__device__ __forceinline__ f32x4 mfma_bf16(s16x8 a, s16x8 b, f32x4 c) {
  return __builtin_amdgcn_mfma_f32_16x16x32_bf16(
      __builtin_bit_cast(bf16x8v, a), __builtin_bit_cast(bf16x8v, b), c, 0, 0, 0);
}

// ---------------- conversion kernels ----------------

__global__ __launch_bounds__(256) void cvt_hs_bf16(const float* __restrict__ in,
                                                   unsigned short* __restrict__ out) {
  int i = (blockIdx.x * 256 + threadIdx.x) * 8;
  float4 v0 = *(const float4*)(in + i);
  float4 v1 = *(const float4*)(in + i + 4);
  u16x8 o;
  o[0] = f32_to_bf16(v0.x); o[1] = f32_to_bf16(v0.y);
  o[2] = f32_to_bf16(v0.z); o[3] = f32_to_bf16(v0.w);
  o[4] = f32_to_bf16(v1.x); o[5] = f32_to_bf16(v1.y);
  o[6] = f32_to_bf16(v1.z); o[7] = f32_to_bf16(v1.w);
  *(u16x8*)(out + i) = o;
}

// WT[n][k] = W[k][n], f32 -> bf16
__global__ __launch_bounds__(256) void transpose_w(const float* __restrict__ W,
                                                   unsigned short* __restrict__ WT) {
  __shared__ float tile[32][33];
  int tx = threadIdx.x & 31;
  int ty = threadIdx.x >> 5;  // 0..7
  int c0 = blockIdx.x * 32;   // n range
  int r0 = blockIdx.y * 32;   // k range
#pragma unroll
  for (int i = 0; i < 4; ++i)
    tile[ty + i * 8][tx] = W[(r0 + ty + i * 8) * D_DIM + c0 + tx];
  __syncthreads();
#pragma unroll
  for (int i = 0; i < 4; ++i)
    WT[(c0 + ty + i * 8) * D_DIM + r0 + tx] = f32_to_bf16(tile[tx][ty + i * 8]);
}

// ---------------- pooling + gate ----------------

// partial[b][chunk][d] = sum over 256 s-rows
__global__ __launch_bounds__(256) void pool_partial(const float* __restrict__ hs,
                                                    float* __restrict__ partial) {
  int bid = blockIdx.x;  // 64 = 2 * 8 * 4
  int b = bid & 1;
  int chunk = (bid >> 1) & 7;
  int dq = bid >> 4;  // 0..3
  int d = dq * 256 + threadIdx.x;
  const float* p = hs + ((size_t)b * S_LEN + chunk * 256) * D_DIM + d;
  float s = 0.f;
  for (int i = 0; i < 256; ++i) s += p[(size_t)i * D_DIM];
  partial[(b * 8 + chunk) * D_DIM + d] = s;
}

__global__ __launch_bounds__(128) void gate_kernel(
    const float* __restrict__ partial, const float* __restrict__ pW1,
    const float* __restrict__ pb1, const float* __restrict__ gamma,
    const float* __restrict__ beta, const float* __restrict__ mean,
    const float* __restrict__ var, const float* __restrict__ pW2,
    const float* __restrict__ pb2, float* __restrict__ gate) {
  __shared__ float pooled[2 * D_DIM];
  __shared__ float hsh[2][64];
  int t = threadIdx.x;
  for (int idx = t; idx < 2 * D_DIM; idx += 128) {
    int b = idx >> 10, k = idx & 1023;
    float s = 0.f;
#pragma unroll
    for (int c = 0; c < 8; ++c) s += partial[(b * 8 + c) * D_DIM + k];
    pooled[idx] = s * (1.0f / 2048.0f);
  }
  __syncthreads();
  int b = t >> 6, j = t & 63;
  float acc = pb1[j];
  for (int k = 0; k < D_DIM; ++k) acc += pooled[b * D_DIM + k] * pW1[k * 64 + j];
  acc = (acc - mean[j]) * rsqrtf(var[j] + 1e-12f) * gamma[j] + beta[j];
  hsh[b][j] = fmaxf(acc, 0.f);
  __syncthreads();
  if (t < 32) {
    int bb = t >> 4, hh = t & 15;
    float lg = pb2[hh];
#pragma unroll
    for (int jj = 0; jj < 64; ++jj) lg += hsh[bb][jj] * pW2[jj * NH + hh];
    gate[bb * NH + hh] = (lg >= 0.f) ? 1.f : 0.f;
  }
}

// ---------------- projection GEMM (bt pattern) ----------------
// C[m][n] = sum_k A[m][k] * BT[n][k]  (+ bias), A,BT bf16 row-major stride 1024.
// mode 0: m = b*S+s, n = h*64+d, out bf16 [b*16+h][s][64]   (Q,K)
// mode 1: m = h*64+d (A = WvT), n = b*S+s (BT = HS), out bf16 [b*16+h][d][2048] (Vt)
#define BM 128
#define BN 128
#define BK 32
#define LDK 40

__global__ __launch_bounds__(256) void proj_gemm(const unsigned short* __restrict__ A,
                                                 const unsigned short* __restrict__ BT,
                                                 const float* __restrict__ bias,
                                                 unsigned short* __restrict__ Cout,
                                                 int mode) {
  __shared__ __align__(16) unsigned short As[BM][LDK];
  __shared__ __align__(16) unsigned short Bs[BN][LDK];
  int m0 = blockIdx.x * BM;
  int n0 = blockIdx.y * BN;
  int tid = threadIdx.x;
  int wave = tid >> 6, lane = tid & 63;
  int l15 = lane & 15, lhi = lane >> 4;
  int wm = (wave >> 1) * 64, wn = (wave & 1) * 64;
  f32x4 acc[4][4] = {};

  for (int k0 = 0; k0 < D_DIM; k0 += BK) {
#pragma unroll
    for (int i = 0; i < 2; ++i) {
      int idx = (tid + i * 256) * 8;
      int r = idx >> 5;
      int c = idx & 31;
      *(u16x8*)&As[r][c] = *(const u16x8*)(A + (size_t)(m0 + r) * D_DIM + k0 + c);
      *(u16x8*)&Bs[r][c] = *(const u16x8*)(BT + (size_t)(n0 + r) * D_DIM + k0 + c);
    }
    __syncthreads();
    s16x8 af[4], bf[4];
#pragma unroll
    for (int mi = 0; mi < 4; ++mi)
      af[mi] = *(const s16x8*)&As[wm + mi * 16 + l15][lhi * 8];
#pragma unroll
    for (int ni = 0; ni < 4; ++ni)
      bf[ni] = *(const s16x8*)&Bs[wn + ni * 16 + l15][lhi * 8];
#pragma unroll
    for (int mi = 0; mi < 4; ++mi)
#pragma unroll
      for (int ni = 0; ni < 4; ++ni)
        acc[mi][ni] = mfma_bf16(af[mi], bf[ni], acc[mi][ni]);
    __syncthreads();
  }

#pragma unroll
  for (int mi = 0; mi < 4; ++mi)
#pragma unroll
    for (int ni = 0; ni < 4; ++ni)
#pragma unroll
      for (int r = 0; r < 4; ++r) {
        int row = m0 + wm + mi * 16 + lhi * 4 + r;
        int col = n0 + wn + ni * 16 + l15;
        float v = acc[mi][ni][r] + ((mode == 1) ? bias[row] : bias[col]);
        unsigned short bv = f32_to_bf16(v);
        if (mode == 0) {
          int b = row >> 11, s = row & 2047;
          int h = col >> 6, d = col & 63;
          Cout[((size_t)(b * NH + h) * S_LEN + s) * HD + d] = bv;
        } else {
          int h = row >> 6, d = row & 63;
          int b = col >> 11, s = col & 2047;
          Cout[((size_t)(b * NH + h) * HD + d) * S_LEN + s] = bv;
        }
      }
}

// ---------------- flash attention ----------------
// grid: (S/64, B*H); 4 waves/block, 16 q-rows per wave, 64-key tiles.
__global__ __launch_bounds__(256) void attn_kernel(
    const unsigned short* __restrict__ Q, const unsigned short* __restrict__ K,
    const unsigned short* __restrict__ Vt, const float* __restrict__ mask,
    const float* __restrict__ gate, float* __restrict__ Out) {
  __shared__ __align__(16) unsigned short p_lds[4][16][72];
  int bh = blockIdx.y;
  int b = bh >> 4, h = bh & 15;
  int wave = threadIdx.x >> 6, lane = threadIdx.x & 63;
  int l15 = lane & 15, lhi = lane >> 4;
  int q0 = blockIdx.x * 64 + wave * 16;

  const unsigned short* Qp = Q + (size_t)bh * S_LEN * HD;
  const unsigned short* Kp = K + (size_t)bh * S_LEN * HD;
  const unsigned short* Vp = Vt + (size_t)bh * HD * S_LEN;

  s16x8 a_q[2];
#pragma unroll
  for (int ks = 0; ks < 2; ++ks)
    a_q[ks] = *(const s16x8*)(Qp + (size_t)(q0 + l15) * HD + ks * 32 + lhi * 8);

  f32x4 o_acc[4] = {};
  float mrow[4], ssum[4];
#pragma unroll
  for (int r = 0; r < 4; ++r) { mrow[r] = -1e30f; ssum[r] = 0.f; }

  const float scl = 0.125f;  // 1/sqrt(64)

  for (int kt = 0; kt < S_LEN; kt += 64) {
    f32x4 sc[4] = {};
#pragma unroll
    for (int ks = 0; ks < 2; ++ks) {
#pragma unroll
      for (int nf = 0; nf < 4; ++nf) {
        s16x8 kf = *(const s16x8*)(Kp + (size_t)(kt + nf * 16 + l15) * HD + ks * 32 + lhi * 8);
        sc[nf] = mfma_bf16(a_q[ks], kf, sc[nf]);
      }
    }

    float mv[4];
#pragma unroll
    for (int nf = 0; nf < 4; ++nf) mv[nf] = mask[b * S_LEN + kt + nf * 16 + l15];

#pragma unroll
    for (int r = 0; r < 4; ++r) {
      float mx = -1e30f;
#pragma unroll
      for (int nf = 0; nf < 4; ++nf) {
        float s = sc[nf][r] * scl + mv[nf];
        sc[nf][r] = s;
        mx = fmaxf(mx, s);
      }
#pragma unroll
      for (int off = 1; off < 16; off <<= 1) mx = fmaxf(mx, __shfl_xor(mx, off, 64));
      float m_new = fmaxf(mrow[r], mx);
      float corr = __expf(mrow[r] - m_new);
      mrow[r] = m_new;
      float psum = 0.f;
#pragma unroll
      for (int nf = 0; nf < 4; ++nf) {
        float p = __expf(sc[nf][r] - m_new);
        sc[nf][r] = p;
        psum += p;
      }
#pragma unroll
      for (int off = 1; off < 16; off <<= 1) psum += __shfl_xor(psum, off, 64);
      ssum[r] = ssum[r] * corr + psum;
#pragma unroll
      for (int df = 0; df < 4; ++df) o_acc[df][r] *= corr;
    }

    __syncthreads();  // WAR: all waves done reading previous P
#pragma unroll
    for (int r = 0; r < 4; ++r)
#pragma unroll
      for (int nf = 0; nf < 4; ++nf)
        p_lds[wave][lhi * 4 + r][nf * 16 + l15] = f32_to_bf16(sc[nf][r]);
    __syncthreads();  // RAW: P visible

#pragma unroll
    for (int ks = 0; ks < 2; ++ks) {
      s16x8 ap = *(const s16x8*)&p_lds[wave][l15][ks * 32 + lhi * 8];
#pragma unroll
      for (int df = 0; df < 4; ++df) {
        s16x8 vf = *(const s16x8*)(Vp + (size_t)(df * 16 + l15) * S_LEN + kt + ks * 32 + lhi * 8);
        o_acc[df] = mfma_bf16(ap, vf, o_acc[df]);
      }
    }
  }

  float g = gate[bh];
#pragma unroll
  for (int r = 0; r < 4; ++r) {
    float inv = g / ssum[r];
    int qrow = q0 + lhi * 4 + r;
#pragma unroll
    for (int df = 0; df < 4; ++df)
      Out[((size_t)b * S_LEN + qrow) * D_DIM + h * HD + df * 16 + l15] = o_acc[df][r] * inv;
  }
}

// ---------------- launch ----------------

extern "C" void kernel_launch(void* const* d_in, const int* in_sizes, int n_in,
                              void* d_out, int out_size, void* d_ws, size_t ws_size,
                              hipStream_t stream) {
  (void)in_sizes; (void)n_in; (void)out_size; (void)ws_size;
  const float* hs   = (const float*)d_in[0];
  const float* mask = (const float*)d_in[1];
  const float* Wq   = (const float*)d_in[2];
  const float* bq   = (const float*)d_in[3];
  const float* Wk   = (const float*)d_in[4];
  const float* bk   = (const float*)d_in[5];
  const float* Wv   = (const float*)d_in[6];
  const float* bv   = (const float*)d_in[7];
  const float* pW1  = (const float*)d_in[8];
  const float* pb1  = (const float*)d_in[9];
  const float* gam  = (const float*)d_in[10];
  const float* bet  = (const float*)d_in[11];
  const float* mea  = (const float*)d_in[12];
  const float* var  = (const float*)d_in[13];
  const float* pW2  = (const float*)d_in[14];
  const float* pb2  = (const float*)d_in[15];
  float* out = (float*)d_out;

  const size_t MB = 1u << 20;
  char* ws = (char*)d_ws;
  unsigned short* hsb = (unsigned short*)(ws);            // 8 MB [4096][1024]
  unsigned short* wTq = (unsigned short*)(ws + 8 * MB);   // 2 MB
  unsigned short* wTk = (unsigned short*)(ws + 10 * MB);  // 2 MB
  unsigned short* wTv = (unsigned short*)(ws + 12 * MB);  // 2 MB
  unsigned short* Qb  = (unsigned short*)(ws + 14 * MB);  // 8 MB [32][2048][64]
  unsigned short* Kb  = (unsigned short*)(ws + 22 * MB);  // 8 MB [32][2048][64]
  unsigned short* Vtb = (unsigned short*)(ws + 30 * MB);  // 8 MB [32][64][2048]
  float* partial = (float*)(ws + 38 * MB);                // 64 KB [2][8][1024]
  float* gateb   = (float*)(ws + 38 * MB + 65536);        // 128 B [32]

  cvt_hs_bf16<<<2048, 256, 0, stream>>>(hs, hsb);
  transpose_w<<<dim3(32, 32), 256, 0, stream>>>(Wq, wTq);
  transpose_w<<<dim3(32, 32), 256, 0, stream>>>(Wk, wTk);
  transpose_w<<<dim3(32, 32), 256, 0, stream>>>(Wv, wTv);
  pool_partial<<<64, 256, 0, stream>>>(hs, partial);
  gate_kernel<<<1, 128, 0, stream>>>(partial, pW1, pb1, gam, bet, mea, var, pW2, pb2, gateb);

  proj_gemm<<<dim3(32, 8), 256, 0, stream>>>(hsb, wTq, bq, Qb, 0);
  proj_gemm<<<dim3(32, 8), 256, 0, stream>>>(hsb, wTk, bk, Kb, 0);
  proj_gemm<<<dim3(8, 32), 256, 0, stream>>>(wTv, hsb, bv, Vtb, 1);

  attn_kernel<<<dim3(32, 32), 256, 0, stream>>>(Qb, Kb, Vtb, mask, gateb, out);
}

// Round 2
// 366.699 us; speedup vs baseline: 1.3356x; 1.3356x over previous
//
#include <hip/hip_runtime.h>

#define S_LEN 2048
#define D_DIM 1024
#define NH 16
#define HD 64
#define BATCH 2

using s16x8 = __attribute__((ext_vector_type(8))) short;
using u16x8 = __attribute__((ext_vector_type(8))) unsigned short;
using f32x4 = __attribute__((ext_vector_type(4))) float;
using bf16x8v = __attribute__((ext_vector_type(8))) __bf16;

__device__ __forceinline__ unsigned short f32_to_bf16(float f) {
  unsigned int u = __float_as_uint(f);
  u += 0x7FFFu + ((u >> 16) & 1u);
  return (unsigned short)(u >> 16);
}

__device__ __forceinline__ f32x4 mfma_bf16(s16x8 a, s16x8 b, f32x4 c) {
  return __builtin_amdgcn_mfma_f32_16x16x32_bf16(
      __builtin_bit_cast(bf16x8v, a), __builtin_bit_cast(bf16x8v, b), c, 0, 0, 0);
}

// ---------------- conversion kernels ----------------

__global__ __launch_bounds__(256) void cvt_hs_bf16(const float* __restrict__ in,
                                                   unsigned short* __restrict__ out) {
  int i = (blockIdx.x * 256 + threadIdx.x) * 8;
  float4 v0 = *(const float4*)(in + i);
  float4 v1 = *(const float4*)(in + i + 4);
  u16x8 o;
  o[0] = f32_to_bf16(v0.x); o[1] = f32_to_bf16(v0.y);
  o[2] = f32_to_bf16(v0.z); o[3] = f32_to_bf16(v0.w);
  o[4] = f32_to_bf16(v1.x); o[5] = f32_to_bf16(v1.y);
  o[6] = f32_to_bf16(v1.z); o[7] = f32_to_bf16(v1.w);
  *(u16x8*)(out + i) = o;
}

// WT[n][k] = W[k][n], f32 -> bf16
__global__ __launch_bounds__(256) void transpose_w(const float* __restrict__ W,
                                                   unsigned short* __restrict__ WT) {
  __shared__ float tile[32][33];
  int tx = threadIdx.x & 31;
  int ty = threadIdx.x >> 5;  // 0..7
  int c0 = blockIdx.x * 32;   // n range
  int r0 = blockIdx.y * 32;   // k range
#pragma unroll
  for (int i = 0; i < 4; ++i)
    tile[ty + i * 8][tx] = W[(r0 + ty + i * 8) * D_DIM + c0 + tx];
  __syncthreads();
#pragma unroll
  for (int i = 0; i < 4; ++i)
    WT[(c0 + ty + i * 8) * D_DIM + r0 + tx] = f32_to_bf16(tile[tx][ty + i * 8]);
}

// ---------------- pooling + gate ----------------

__global__ __launch_bounds__(256) void pool_partial(const float* __restrict__ hs,
                                                    float* __restrict__ partial) {
  int bid = blockIdx.x;  // 64 = 2 * 8 * 4
  int b = bid & 1;
  int chunk = (bid >> 1) & 7;
  int dq = bid >> 4;  // 0..3
  int d = dq * 256 + threadIdx.x;
  const float* p = hs + ((size_t)b * S_LEN + chunk * 256) * D_DIM + d;
  float s = 0.f;
  for (int i = 0; i < 256; ++i) s += p[(size_t)i * D_DIM];
  partial[(b * 8 + chunk) * D_DIM + d] = s;
}

__global__ __launch_bounds__(128) void gate_kernel(
    const float* __restrict__ partial, const float* __restrict__ pW1,
    const float* __restrict__ pb1, const float* __restrict__ gamma,
    const float* __restrict__ beta, const float* __restrict__ mean,
    const float* __restrict__ var, const float* __restrict__ pW2,
    const float* __restrict__ pb2, float* __restrict__ gate) {
  __shared__ float pooled[2 * D_DIM];
  __shared__ float hsh[2][64];
  int t = threadIdx.x;
  for (int idx = t; idx < 2 * D_DIM; idx += 128) {
    int b = idx >> 10, k = idx & 1023;
    float s = 0.f;
#pragma unroll
    for (int c = 0; c < 8; ++c) s += partial[(b * 8 + c) * D_DIM + k];
    pooled[idx] = s * (1.0f / 2048.0f);
  }
  __syncthreads();
  int b = t >> 6, j = t & 63;
  float acc = pb1[j];
  for (int k = 0; k < D_DIM; ++k) acc += pooled[b * D_DIM + k] * pW1[k * 64 + j];
  acc = (acc - mean[j]) * rsqrtf(var[j] + 1e-12f) * gamma[j] + beta[j];
  hsh[b][j] = fmaxf(acc, 0.f);
  __syncthreads();
  if (t < 32) {
    int bb = t >> 4, hh = t & 15;
    float lg = pb2[hh];
#pragma unroll
    for (int jj = 0; jj < 64; ++jj) lg += hsh[bb][jj] * pW2[jj * NH + hh];
    gate[bb * NH + hh] = (lg >= 0.f) ? 1.f : 0.f;
  }
}

// ---------------- projection GEMM (bt pattern) ----------------
#define BM 128
#define BN 128
#define BK 32
#define LDK 40

__global__ __launch_bounds__(256) void proj_gemm(const unsigned short* __restrict__ A,
                                                 const unsigned short* __restrict__ BT,
                                                 const float* __restrict__ bias,
                                                 unsigned short* __restrict__ Cout,
                                                 int mode) {
  __shared__ __align__(16) unsigned short As[BM][LDK];
  __shared__ __align__(16) unsigned short Bs[BN][LDK];
  int m0 = blockIdx.x * BM;
  int n0 = blockIdx.y * BN;
  int tid = threadIdx.x;
  int wave = tid >> 6, lane = tid & 63;
  int l15 = lane & 15, lhi = lane >> 4;
  int wm = (wave >> 1) * 64, wn = (wave & 1) * 64;
  f32x4 acc[4][4] = {};

  for (int k0 = 0; k0 < D_DIM; k0 += BK) {
#pragma unroll
    for (int i = 0; i < 2; ++i) {
      int idx = (tid + i * 256) * 8;
      int r = idx >> 5;
      int c = idx & 31;
      *(u16x8*)&As[r][c] = *(const u16x8*)(A + (size_t)(m0 + r) * D_DIM + k0 + c);
      *(u16x8*)&Bs[r][c] = *(const u16x8*)(BT + (size_t)(n0 + r) * D_DIM + k0 + c);
    }
    __syncthreads();
    s16x8 af[4], bf[4];
#pragma unroll
    for (int mi = 0; mi < 4; ++mi)
      af[mi] = *(const s16x8*)&As[wm + mi * 16 + l15][lhi * 8];
#pragma unroll
    for (int ni = 0; ni < 4; ++ni)
      bf[ni] = *(const s16x8*)&Bs[wn + ni * 16 + l15][lhi * 8];
#pragma unroll
    for (int mi = 0; mi < 4; ++mi)
#pragma unroll
      for (int ni = 0; ni < 4; ++ni)
        acc[mi][ni] = mfma_bf16(af[mi], bf[ni], acc[mi][ni]);
    __syncthreads();
  }

#pragma unroll
  for (int mi = 0; mi < 4; ++mi)
#pragma unroll
    for (int ni = 0; ni < 4; ++ni)
#pragma unroll
      for (int r = 0; r < 4; ++r) {
        int row = m0 + wm + mi * 16 + lhi * 4 + r;
        int col = n0 + wn + ni * 16 + l15;
        float v = acc[mi][ni][r] + ((mode == 1) ? bias[row] : bias[col]);
        unsigned short bv = f32_to_bf16(v);
        if (mode == 0) {
          int b = row >> 11, s = row & 2047;
          int h = col >> 6, d = col & 63;
          Cout[((size_t)(b * NH + h) * S_LEN + s) * HD + d] = bv;
        } else {
          int h = row >> 6, d = row & 63;
          int b = col >> 11, s = col & 2047;
          Cout[((size_t)(b * NH + h) * HD + d) * S_LEN + s] = bv;
        }
      }
}

// ---------------- flash attention (swapped-operand, lane-local softmax) ----------------
// grid: (S/64, B*H); 4 waves/block, 16 q-rows per wave, 64-key tiles.
// S^T = mfma(K_frag, Q_frag): lane holds S[q=l15][key=nf*16+lhi*4+r] in sc[nf][r]
// O^T = mfma(Vt_frag, P_frag): lane holds O[q=l15][d=df*16+lhi*4+r] in o_acc[df][r]
// -> softmax stats (max/sum/rescale) are lane-local scalars; zero barriers.
__global__ __launch_bounds__(256) void attn_kernel(
    const unsigned short* __restrict__ Q, const unsigned short* __restrict__ K,
    const unsigned short* __restrict__ Vt, const float* __restrict__ mask,
    const float* __restrict__ gate, float* __restrict__ Out) {
  __shared__ __align__(16) unsigned short p_lds[4][2][16][72];
  int bh = blockIdx.y;
  int b = bh >> 4, h = bh & 15;
  int wave = threadIdx.x >> 6, lane = threadIdx.x & 63;
  int l15 = lane & 15, lhi = lane >> 4;
  int q0 = blockIdx.x * 64 + wave * 16;
  int qrow = q0 + l15;

  float g = gate[bh];
  if (g == 0.f) {
    // gated-off head: context is exactly zero
    float4 z = {0.f, 0.f, 0.f, 0.f};
#pragma unroll
    for (int dd = 0; dd < 4; ++dd)
      *(float4*)(Out + ((size_t)b * S_LEN + qrow) * D_DIM + h * HD + lhi * 16 + dd * 4) = z;
    return;
  }

  const unsigned short* Qp = Q + (size_t)bh * S_LEN * HD;
  const unsigned short* Kp = K + (size_t)bh * S_LEN * HD;
  const unsigned short* Vp = Vt + (size_t)bh * HD * S_LEN;

  s16x8 q_frag[2];
#pragma unroll
  for (int ks = 0; ks < 2; ++ks)
    q_frag[ks] = *(const s16x8*)(Qp + (size_t)qrow * HD + ks * 32 + lhi * 8);

  f32x4 o_acc[4] = {};
  float m_run = -1e30f, s_run = 0.f;
  const float scl = 0.125f;  // 1/sqrt(64)

  for (int kt = 0; kt < S_LEN; kt += 64) {
    int par = (kt >> 6) & 1;
    // ---- S^T = K · Q^T : sc[nf][r] = S[q=l15][key=kt+nf*16+lhi*4+r]
    f32x4 sc[4] = {};
#pragma unroll
    for (int ks = 0; ks < 2; ++ks) {
#pragma unroll
      for (int nf = 0; nf < 4; ++nf) {
        s16x8 kf = *(const s16x8*)(Kp + (size_t)(kt + nf * 16 + l15) * HD + ks * 32 + lhi * 8);
        sc[nf] = mfma_bf16(kf, q_frag[ks], sc[nf]);
      }
    }

    // ---- scale + mask + lane-local row max (keys spread over regs x lhi)
    float mx = -1e30f;
#pragma unroll
    for (int nf = 0; nf < 4; ++nf) {
      float4 mv = *(const float4*)(mask + (size_t)b * S_LEN + kt + nf * 16 + lhi * 4);
#pragma unroll
      for (int r = 0; r < 4; ++r) {
        float s = sc[nf][r] * scl + ((const float*)&mv)[r];
        sc[nf][r] = s;
        mx = fmaxf(mx, s);
      }
    }
    mx = fmaxf(mx, __shfl_xor(mx, 16, 64));
    mx = fmaxf(mx, __shfl_xor(mx, 32, 64));

    float m_new = fmaxf(m_run, mx);
    float corr = __expf(m_run - m_new);
    m_run = m_new;

    float ps = 0.f;
#pragma unroll
    for (int nf = 0; nf < 4; ++nf)
#pragma unroll
      for (int r = 0; r < 4; ++r) {
        float p = __expf(sc[nf][r] - m_new);
        sc[nf][r] = p;
        ps += p;
      }
    ps += __shfl_xor(ps, 16, 64);
    ps += __shfl_xor(ps, 32, 64);
    s_run = s_run * corr + ps;

#pragma unroll
    for (int df = 0; df < 4; ++df)
#pragma unroll
      for (int r = 0; r < 4; ++r) o_acc[df][r] *= corr;

    // ---- P -> LDS (per-wave slice, parity double-buffered, no barriers)
#pragma unroll
    for (int nf = 0; nf < 4; ++nf) {
      unsigned int lo = (unsigned int)f32_to_bf16(sc[nf][0]) |
                        ((unsigned int)f32_to_bf16(sc[nf][1]) << 16);
      unsigned int hi = (unsigned int)f32_to_bf16(sc[nf][2]) |
                        ((unsigned int)f32_to_bf16(sc[nf][3]) << 16);
      uint2 pk = {lo, hi};
      *(uint2*)&p_lds[wave][par][l15][nf * 16 + lhi * 4] = pk;
    }

    // ---- O^T += V^T · P^T
#pragma unroll
    for (int ks = 0; ks < 2; ++ks) {
      s16x8 pf = *(const s16x8*)&p_lds[wave][par][l15][ks * 32 + lhi * 8];
#pragma unroll
      for (int df = 0; df < 4; ++df) {
        s16x8 vf = *(const s16x8*)(Vp + (size_t)(df * 16 + l15) * S_LEN + kt + ks * 32 + lhi * 8);
        o_acc[df] = mfma_bf16(vf, pf, o_acc[df]);
      }
    }
  }

  float inv = g / s_run;
#pragma unroll
  for (int df = 0; df < 4; ++df) {
    float4 ov;
    ov.x = o_acc[df][0] * inv;
    ov.y = o_acc[df][1] * inv;
    ov.z = o_acc[df][2] * inv;
    ov.w = o_acc[df][3] * inv;
    *(float4*)(Out + ((size_t)b * S_LEN + qrow) * D_DIM + h * HD + df * 16 + lhi * 4) = ov;
  }
}

// ---------------- launch ----------------

extern "C" void kernel_launch(void* const* d_in, const int* in_sizes, int n_in,
                              void* d_out, int out_size, void* d_ws, size_t ws_size,
                              hipStream_t stream) {
  (void)in_sizes; (void)n_in; (void)out_size; (void)ws_size;
  const float* hs   = (const float*)d_in[0];
  const float* mask = (const float*)d_in[1];
  const float* Wq   = (const float*)d_in[2];
  const float* bq   = (const float*)d_in[3];
  const float* Wk   = (const float*)d_in[4];
  const float* bk   = (const float*)d_in[5];
  const float* Wv   = (const float*)d_in[6];
  const float* bv   = (const float*)d_in[7];
  const float* pW1  = (const float*)d_in[8];
  const float* pb1  = (const float*)d_in[9];
  const float* gam  = (const float*)d_in[10];
  const float* bet  = (const float*)d_in[11];
  const float* mea  = (const float*)d_in[12];
  const float* var  = (const float*)d_in[13];
  const float* pW2  = (const float*)d_in[14];
  const float* pb2  = (const float*)d_in[15];
  float* out = (float*)d_out;

  const size_t MB = 1u << 20;
  char* ws = (char*)d_ws;
  unsigned short* hsb = (unsigned short*)(ws);            // 8 MB [4096][1024]
  unsigned short* wTq = (unsigned short*)(ws + 8 * MB);   // 2 MB
  unsigned short* wTk = (unsigned short*)(ws + 10 * MB);  // 2 MB
  unsigned short* wTv = (unsigned short*)(ws + 12 * MB);  // 2 MB
  unsigned short* Qb  = (unsigned short*)(ws + 14 * MB);  // 8 MB [32][2048][64]
  unsigned short* Kb  = (unsigned short*)(ws + 22 * MB);  // 8 MB [32][2048][64]
  unsigned short* Vtb = (unsigned short*)(ws + 30 * MB);  // 8 MB [32][64][2048]
  float* partial = (float*)(ws + 38 * MB);                // 64 KB [2][8][1024]
  float* gateb   = (float*)(ws + 38 * MB + 65536);        // 128 B [32]

  cvt_hs_bf16<<<2048, 256, 0, stream>>>(hs, hsb);
  transpose_w<<<dim3(32, 32), 256, 0, stream>>>(Wq, wTq);
  transpose_w<<<dim3(32, 32), 256, 0, stream>>>(Wk, wTk);
  transpose_w<<<dim3(32, 32), 256, 0, stream>>>(Wv, wTv);
  pool_partial<<<64, 256, 0, stream>>>(hs, partial);
  gate_kernel<<<1, 128, 0, stream>>>(partial, pW1, pb1, gam, bet, mea, var, pW2, pb2, gateb);

  proj_gemm<<<dim3(32, 8), 256, 0, stream>>>(hsb, wTq, bq, Qb, 0);
  proj_gemm<<<dim3(32, 8), 256, 0, stream>>>(hsb, wTk, bk, Kb, 0);
  proj_gemm<<<dim3(8, 32), 256, 0, stream>>>(wTv, hsb, bv, Vtb, 1);

  attn_kernel<<<dim3(32, 32), 256, 0, stream>>>(Qb, Kb, Vtb, mask, gateb, out);
}

// Round 3
// 357.826 us; speedup vs baseline: 1.3687x; 1.0248x over previous
//
#include <hip/hip_runtime.h>

#define S_LEN 2048
#define D_DIM 1024
#define NH 16
#define HD 64
#define BATCH 2

using s16x8 = __attribute__((ext_vector_type(8))) short;
using u16x8 = __attribute__((ext_vector_type(8))) unsigned short;
using f32x4 = __attribute__((ext_vector_type(4))) float;
using bf16x8v = __attribute__((ext_vector_type(8))) __bf16;

__device__ __forceinline__ unsigned short f32_to_bf16(float f) {
  unsigned int u = __float_as_uint(f);
  u += 0x7FFFu + ((u >> 16) & 1u);
  return (unsigned short)(u >> 16);
}

__device__ __forceinline__ f32x4 mfma_bf16(s16x8 a, s16x8 b, f32x4 c) {
  return __builtin_amdgcn_mfma_f32_16x16x32_bf16(
      __builtin_bit_cast(bf16x8v, a), __builtin_bit_cast(bf16x8v, b), c, 0, 0, 0);
}

// ---------------- conversion kernels ----------------

__global__ __launch_bounds__(256) void cvt_hs_bf16(const float* __restrict__ in,
                                                   unsigned short* __restrict__ out) {
  int i = (blockIdx.x * 256 + threadIdx.x) * 8;
  float4 v0 = *(const float4*)(in + i);
  float4 v1 = *(const float4*)(in + i + 4);
  u16x8 o;
  o[0] = f32_to_bf16(v0.x); o[1] = f32_to_bf16(v0.y);
  o[2] = f32_to_bf16(v0.z); o[3] = f32_to_bf16(v0.w);
  o[4] = f32_to_bf16(v1.x); o[5] = f32_to_bf16(v1.y);
  o[6] = f32_to_bf16(v1.z); o[7] = f32_to_bf16(v1.w);
  *(u16x8*)(out + i) = o;
}

// WT[n][k] = W[k][n], f32 -> bf16
__global__ __launch_bounds__(256) void transpose_w(const float* __restrict__ W,
                                                   unsigned short* __restrict__ WT) {
  __shared__ float tile[32][33];
  int tx = threadIdx.x & 31;
  int ty = threadIdx.x >> 5;  // 0..7
  int c0 = blockIdx.x * 32;   // n range
  int r0 = blockIdx.y * 32;   // k range
#pragma unroll
  for (int i = 0; i < 4; ++i)
    tile[ty + i * 8][tx] = W[(r0 + ty + i * 8) * D_DIM + c0 + tx];
  __syncthreads();
#pragma unroll
  for (int i = 0; i < 4; ++i)
    WT[(c0 + ty + i * 8) * D_DIM + r0 + tx] = f32_to_bf16(tile[tx][ty + i * 8]);
}

// ---------------- pooling + gate ----------------

__global__ __launch_bounds__(256) void pool_partial(const float* __restrict__ hs,
                                                    float* __restrict__ partial) {
  int bid = blockIdx.x;  // 64 = 2 * 8 * 4
  int b = bid & 1;
  int chunk = (bid >> 1) & 7;
  int dq = bid >> 4;  // 0..3
  int d = dq * 256 + threadIdx.x;
  const float* p = hs + ((size_t)b * S_LEN + chunk * 256) * D_DIM + d;
  float s = 0.f;
  for (int i = 0; i < 256; ++i) s += p[(size_t)i * D_DIM];
  partial[(b * 8 + chunk) * D_DIM + d] = s;
}

__global__ __launch_bounds__(128) void gate_kernel(
    const float* __restrict__ partial, const float* __restrict__ pW1,
    const float* __restrict__ pb1, const float* __restrict__ gamma,
    const float* __restrict__ beta, const float* __restrict__ mean,
    const float* __restrict__ var, const float* __restrict__ pW2,
    const float* __restrict__ pb2, float* __restrict__ gate) {
  __shared__ float pooled[2 * D_DIM];
  __shared__ float hsh[2][64];
  int t = threadIdx.x;
  for (int idx = t; idx < 2 * D_DIM; idx += 128) {
    int b = idx >> 10, k = idx & 1023;
    float s = 0.f;
#pragma unroll
    for (int c = 0; c < 8; ++c) s += partial[(b * 8 + c) * D_DIM + k];
    pooled[idx] = s * (1.0f / 2048.0f);
  }
  __syncthreads();
  int b = t >> 6, j = t & 63;
  float acc = pb1[j];
  for (int k = 0; k < D_DIM; ++k) acc += pooled[b * D_DIM + k] * pW1[k * 64 + j];
  acc = (acc - mean[j]) * rsqrtf(var[j] + 1e-12f) * gamma[j] + beta[j];
  hsh[b][j] = fmaxf(acc, 0.f);
  __syncthreads();
  if (t < 32) {
    int bb = t >> 4, hh = t & 15;
    float lg = pb2[hh];
#pragma unroll
    for (int jj = 0; jj < 64; ++jj) lg += hsh[bb][jj] * pW2[jj * NH + hh];
    gate[bb * NH + hh] = (lg >= 0.f) ? 1.f : 0.f;
  }
}

// ---------------- projection GEMM (bt pattern) ----------------
#define BM 128
#define BN 128
#define BK 32
#define LDK 40

__global__ __launch_bounds__(256) void proj_gemm(const unsigned short* __restrict__ A,
                                                 const unsigned short* __restrict__ BT,
                                                 const float* __restrict__ bias,
                                                 unsigned short* __restrict__ Cout,
                                                 int mode) {
  __shared__ __align__(16) unsigned short As[BM][LDK];
  __shared__ __align__(16) unsigned short Bs[BN][LDK];
  int m0 = blockIdx.x * BM;
  int n0 = blockIdx.y * BN;
  int tid = threadIdx.x;
  int wave = tid >> 6, lane = tid & 63;
  int l15 = lane & 15, lhi = lane >> 4;
  int wm = (wave >> 1) * 64, wn = (wave & 1) * 64;
  f32x4 acc[4][4] = {};

  for (int k0 = 0; k0 < D_DIM; k0 += BK) {
#pragma unroll
    for (int i = 0; i < 2; ++i) {
      int idx = (tid + i * 256) * 8;
      int r = idx >> 5;
      int c = idx & 31;
      *(u16x8*)&As[r][c] = *(const u16x8*)(A + (size_t)(m0 + r) * D_DIM + k0 + c);
      *(u16x8*)&Bs[r][c] = *(const u16x8*)(BT + (size_t)(n0 + r) * D_DIM + k0 + c);
    }
    __syncthreads();
    s16x8 af[4], bf[4];
#pragma unroll
    for (int mi = 0; mi < 4; ++mi)
      af[mi] = *(const s16x8*)&As[wm + mi * 16 + l15][lhi * 8];
#pragma unroll
    for (int ni = 0; ni < 4; ++ni)
      bf[ni] = *(const s16x8*)&Bs[wn + ni * 16 + l15][lhi * 8];
#pragma unroll
    for (int mi = 0; mi < 4; ++mi)
#pragma unroll
      for (int ni = 0; ni < 4; ++ni)
        acc[mi][ni] = mfma_bf16(af[mi], bf[ni], acc[mi][ni]);
    __syncthreads();
  }

#pragma unroll
  for (int mi = 0; mi < 4; ++mi)
#pragma unroll
    for (int ni = 0; ni < 4; ++ni)
#pragma unroll
      for (int r = 0; r < 4; ++r) {
        int row = m0 + wm + mi * 16 + lhi * 4 + r;
        int col = n0 + wn + ni * 16 + l15;
        float v = acc[mi][ni][r] + ((mode == 1) ? bias[row] : bias[col]);
        unsigned short bv = f32_to_bf16(v);
        if (mode == 0) {
          int b = row >> 11, s = row & 2047;
          int h = col >> 6, d = col & 63;
          Cout[((size_t)(b * NH + h) * S_LEN + s) * HD + d] = bv;
        } else {
          int h = row >> 6, d = row & 63;
          int b = col >> 11, s = col & 2047;
          Cout[((size_t)(b * NH + h) * HD + d) * S_LEN + s] = bv;
        }
      }
}

// ---------------- flash attention (swapped softmax + K/V issue-early prefetch) ----------------
// grid: 1024 blocks, idx -> bh = idx & 31 (load balance + per-XCD K/V locality),
// qc = idx >> 5. 4 waves/block, 16 q-rows/wave, 64-key tiles.
// Pipeline per tile: QK^T(kf) -> issue V_t -> issue K_{t+1} -> softmax (covers
// V latency) -> PV (vmcnt(8) counted wait) -> next QK (kf complete by then).
__global__ __launch_bounds__(256) void attn_kernel(
    const unsigned short* __restrict__ Q, const unsigned short* __restrict__ K,
    const unsigned short* __restrict__ Vt, const float* __restrict__ mask,
    const float* __restrict__ gate, float* __restrict__ Out) {
  __shared__ __align__(16) unsigned short p_lds[4][2][16][72];
  __shared__ __align__(16) float mask_lds[S_LEN];
  int idx = blockIdx.x;
  int bh = idx & 31;
  int qc = idx >> 5;
  int b = bh >> 4, h = bh & 15;
  int wave = threadIdx.x >> 6, lane = threadIdx.x & 63;
  int l15 = lane & 15, lhi = lane >> 4;
  int q0 = qc * 64 + wave * 16;
  int qrow = q0 + l15;

  float g = gate[bh];
  if (g == 0.f) {  // gated-off head: context is exactly zero (block-uniform exit)
    float4 z = {0.f, 0.f, 0.f, 0.f};
#pragma unroll
    for (int dd = 0; dd < 4; ++dd)
      *(float4*)(Out + ((size_t)b * S_LEN + qrow) * D_DIM + h * HD + lhi * 16 + dd * 4) = z;
    return;
  }

  // stage the mask row for this batch into LDS (one-time)
  for (int i = threadIdx.x * 4; i < S_LEN; i += 256 * 4)
    *(float4*)&mask_lds[i] = *(const float4*)(mask + (size_t)b * S_LEN + i);
  __syncthreads();

  const unsigned short* Qp = Q + (size_t)bh * S_LEN * HD;
  const unsigned short* Kp = K + (size_t)bh * S_LEN * HD;
  const unsigned short* Vp = Vt + (size_t)bh * HD * S_LEN;

  s16x8 q_frag[2];
#pragma unroll
  for (int ks = 0; ks < 2; ++ks)
    q_frag[ks] = *(const s16x8*)(Qp + (size_t)qrow * HD + ks * 32 + lhi * 8);

  f32x4 o_acc[4] = {};
  float m_run = -1e30f, s_run = 0.f;
  const float scl = 0.125f;  // 1/sqrt(64)

  // prologue: prefetch K tile 0
  s16x8 kf[8];
#pragma unroll
  for (int ks = 0; ks < 2; ++ks)
#pragma unroll
    for (int nf = 0; nf < 4; ++nf)
      kf[ks * 4 + nf] =
          *(const s16x8*)(Kp + (size_t)(nf * 16 + l15) * HD + ks * 32 + lhi * 8);

  for (int kt = 0; kt < S_LEN; kt += 64) {
    int par = (kt >> 6) & 1;

    // ---- S^T = K · Q^T : sc[nf][r] = S[q=l15][key=kt+nf*16+lhi*4+r]
    f32x4 sc[4] = {};
#pragma unroll
    for (int ks = 0; ks < 2; ++ks)
#pragma unroll
      for (int nf = 0; nf < 4; ++nf)
        sc[nf] = mfma_bf16(kf[ks * 4 + nf], q_frag[ks], sc[nf]);

    // ---- issue V_t loads (consumed after softmax -> latency hidden)
    s16x8 vf[8];
#pragma unroll
    for (int ks = 0; ks < 2; ++ks)
#pragma unroll
      for (int df = 0; df < 4; ++df)
        vf[ks * 4 + df] = *(const s16x8*)(Vp + (size_t)(df * 16 + l15) * S_LEN + kt +
                                          ks * 32 + lhi * 8);

    // ---- issue K_{t+1} loads (consumed next iteration; wraps harmlessly)
    int ktn = (kt + 64) & (S_LEN - 1);
#pragma unroll
    for (int ks = 0; ks < 2; ++ks)
#pragma unroll
      for (int nf = 0; nf < 4; ++nf)
        kf[ks * 4 + nf] = *(const s16x8*)(Kp + (size_t)(ktn + nf * 16 + l15) * HD +
                                          ks * 32 + lhi * 8);

    // ---- softmax (lane-local stats; overlaps in-flight V/K loads)
    float mx = -1e30f;
#pragma unroll
    for (int nf = 0; nf < 4; ++nf) {
      float4 mv = *(const float4*)&mask_lds[kt + nf * 16 + lhi * 4];
#pragma unroll
      for (int r = 0; r < 4; ++r) {
        float s = sc[nf][r] * scl + ((const float*)&mv)[r];
        sc[nf][r] = s;
        mx = fmaxf(mx, s);
      }
    }
    mx = fmaxf(mx, __shfl_xor(mx, 16, 64));
    mx = fmaxf(mx, __shfl_xor(mx, 32, 64));

    float m_new = fmaxf(m_run, mx);
    float corr = __expf(m_run - m_new);
    m_run = m_new;

    float ps = 0.f;
#pragma unroll
    for (int nf = 0; nf < 4; ++nf)
#pragma unroll
      for (int r = 0; r < 4; ++r) {
        float p = __expf(sc[nf][r] - m_new);
        sc[nf][r] = p;
        ps += p;
      }
    ps += __shfl_xor(ps, 16, 64);
    ps += __shfl_xor(ps, 32, 64);
    s_run = s_run * corr + ps;

#pragma unroll
    for (int df = 0; df < 4; ++df)
#pragma unroll
      for (int r = 0; r < 4; ++r) o_acc[df][r] *= corr;

    // ---- P -> LDS (per-wave slice, parity double-buffered, no barriers)
#pragma unroll
    for (int nf = 0; nf < 4; ++nf) {
      unsigned int lo = (unsigned int)f32_to_bf16(sc[nf][0]) |
                        ((unsigned int)f32_to_bf16(sc[nf][1]) << 16);
      unsigned int hi = (unsigned int)f32_to_bf16(sc[nf][2]) |
                        ((unsigned int)f32_to_bf16(sc[nf][3]) << 16);
      uint2 pk = {lo, hi};
      *(uint2*)&p_lds[wave][par][l15][nf * 16 + lhi * 4] = pk;
    }

    // ---- O^T += V^T · P^T  (vf wait is counted: K_{t+1} stays in flight)
#pragma unroll
    for (int ks = 0; ks < 2; ++ks) {
      s16x8 pf = *(const s16x8*)&p_lds[wave][par][l15][ks * 32 + lhi * 8];
#pragma unroll
      for (int df = 0; df < 4; ++df)
        o_acc[df] = mfma_bf16(vf[ks * 4 + df], pf, o_acc[df]);
    }
  }

  float inv = g / s_run;
#pragma unroll
  for (int df = 0; df < 4; ++df) {
    float4 ov;
    ov.x = o_acc[df][0] * inv;
    ov.y = o_acc[df][1] * inv;
    ov.z = o_acc[df][2] * inv;
    ov.w = o_acc[df][3] * inv;
    *(float4*)(Out + ((size_t)b * S_LEN + qrow) * D_DIM + h * HD + df * 16 + lhi * 4) = ov;
  }
}

// ---------------- launch ----------------

extern "C" void kernel_launch(void* const* d_in, const int* in_sizes, int n_in,
                              void* d_out, int out_size, void* d_ws, size_t ws_size,
                              hipStream_t stream) {
  (void)in_sizes; (void)n_in; (void)out_size; (void)ws_size;
  const float* hs   = (const float*)d_in[0];
  const float* mask = (const float*)d_in[1];
  const float* Wq   = (const float*)d_in[2];
  const float* bq   = (const float*)d_in[3];
  const float* Wk   = (const float*)d_in[4];
  const float* bk   = (const float*)d_in[5];
  const float* Wv   = (const float*)d_in[6];
  const float* bv   = (const float*)d_in[7];
  const float* pW1  = (const float*)d_in[8];
  const float* pb1  = (const float*)d_in[9];
  const float* gam  = (const float*)d_in[10];
  const float* bet  = (const float*)d_in[11];
  const float* mea  = (const float*)d_in[12];
  const float* var  = (const float*)d_in[13];
  const float* pW2  = (const float*)d_in[14];
  const float* pb2  = (const float*)d_in[15];
  float* out = (float*)d_out;

  const size_t MB = 1u << 20;
  char* ws = (char*)d_ws;
  unsigned short* hsb = (unsigned short*)(ws);            // 8 MB [4096][1024]
  unsigned short* wTq = (unsigned short*)(ws + 8 * MB);   // 2 MB
  unsigned short* wTk = (unsigned short*)(ws + 10 * MB);  // 2 MB
  unsigned short* wTv = (unsigned short*)(ws + 12 * MB);  // 2 MB
  unsigned short* Qb  = (unsigned short*)(ws + 14 * MB);  // 8 MB [32][2048][64]
  unsigned short* Kb  = (unsigned short*)(ws + 22 * MB);  // 8 MB [32][2048][64]
  unsigned short* Vtb = (unsigned short*)(ws + 30 * MB);  // 8 MB [32][64][2048]
  float* partial = (float*)(ws + 38 * MB);                // 64 KB [2][8][1024]
  float* gateb   = (float*)(ws + 38 * MB + 65536);        // 128 B [32]

  cvt_hs_bf16<<<2048, 256, 0, stream>>>(hs, hsb);
  transpose_w<<<dim3(32, 32), 256, 0, stream>>>(Wq, wTq);
  transpose_w<<<dim3(32, 32), 256, 0, stream>>>(Wk, wTk);
  transpose_w<<<dim3(32, 32), 256, 0, stream>>>(Wv, wTv);
  pool_partial<<<64, 256, 0, stream>>>(hs, partial);
  gate_kernel<<<1, 128, 0, stream>>>(partial, pW1, pb1, gam, bet, mea, var, pW2, pb2, gateb);

  proj_gemm<<<dim3(32, 8), 256, 0, stream>>>(hsb, wTq, bq, Qb, 0);
  proj_gemm<<<dim3(32, 8), 256, 0, stream>>>(hsb, wTk, bk, Kb, 0);
  proj_gemm<<<dim3(8, 32), 256, 0, stream>>>(wTv, hsb, bv, Vtb, 1);

  attn_kernel<<<1024, 256, 0, stream>>>(Qb, Kb, Vtb, mask, gateb, out);
}

// Round 4
// 222.026 us; speedup vs baseline: 2.2058x; 1.6116x over previous
//
#include <hip/hip_runtime.h>

#define S_LEN 2048
#define D_DIM 1024
#define NH 16
#define HD 64
#define BATCH 2

using s16x8 = __attribute__((ext_vector_type(8))) short;
using u16x8 = __attribute__((ext_vector_type(8))) unsigned short;
using f32x4 = __attribute__((ext_vector_type(4))) float;
using bf16x8v = __attribute__((ext_vector_type(8))) __bf16;

typedef const __attribute__((address_space(1))) unsigned int* gas_ptr;
typedef __attribute__((address_space(3))) unsigned int* las_ptr;

__device__ __forceinline__ unsigned short f32_to_bf16(float f) {
  unsigned int u = __float_as_uint(f);
  u += 0x7FFFu + ((u >> 16) & 1u);
  return (unsigned short)(u >> 16);
}

__device__ __forceinline__ f32x4 mfma_bf16(s16x8 a, s16x8 b, f32x4 c) {
  return __builtin_amdgcn_mfma_f32_16x16x32_bf16(
      __builtin_bit_cast(bf16x8v, a), __builtin_bit_cast(bf16x8v, b), c, 0, 0, 0);
}

// ---------------- conversion kernels ----------------

__global__ __launch_bounds__(256) void cvt_hs_bf16(const float* __restrict__ in,
                                                   unsigned short* __restrict__ out) {
  int i = (blockIdx.x * 256 + threadIdx.x) * 8;
  float4 v0 = *(const float4*)(in + i);
  float4 v1 = *(const float4*)(in + i + 4);
  u16x8 o;
  o[0] = f32_to_bf16(v0.x); o[1] = f32_to_bf16(v0.y);
  o[2] = f32_to_bf16(v0.z); o[3] = f32_to_bf16(v0.w);
  o[4] = f32_to_bf16(v1.x); o[5] = f32_to_bf16(v1.y);
  o[6] = f32_to_bf16(v1.z); o[7] = f32_to_bf16(v1.w);
  *(u16x8*)(out + i) = o;
}

// WT[n][k] = W[k][n], f32 -> bf16
__global__ __launch_bounds__(256) void transpose_w(const float* __restrict__ W,
                                                   unsigned short* __restrict__ WT) {
  __shared__ float tile[32][33];
  int tx = threadIdx.x & 31;
  int ty = threadIdx.x >> 5;  // 0..7
  int c0 = blockIdx.x * 32;   // n range
  int r0 = blockIdx.y * 32;   // k range
#pragma unroll
  for (int i = 0; i < 4; ++i)
    tile[ty + i * 8][tx] = W[(r0 + ty + i * 8) * D_DIM + c0 + tx];
  __syncthreads();
#pragma unroll
  for (int i = 0; i < 4; ++i)
    WT[(c0 + ty + i * 8) * D_DIM + r0 + tx] = f32_to_bf16(tile[tx][ty + i * 8]);
}

// ---------------- pooling + gate ----------------

__global__ __launch_bounds__(256) void pool_partial(const float* __restrict__ hs,
                                                    float* __restrict__ partial) {
  int bid = blockIdx.x;  // 64 = 2 * 8 * 4
  int b = bid & 1;
  int chunk = (bid >> 1) & 7;
  int dq = bid >> 4;  // 0..3
  int d = dq * 256 + threadIdx.x;
  const float* p = hs + ((size_t)b * S_LEN + chunk * 256) * D_DIM + d;
  float s = 0.f;
  for (int i = 0; i < 256; ++i) s += p[(size_t)i * D_DIM];
  partial[(b * 8 + chunk) * D_DIM + d] = s;
}

__global__ __launch_bounds__(128) void gate_kernel(
    const float* __restrict__ partial, const float* __restrict__ pW1,
    const float* __restrict__ pb1, const float* __restrict__ gamma,
    const float* __restrict__ beta, const float* __restrict__ mean,
    const float* __restrict__ var, const float* __restrict__ pW2,
    const float* __restrict__ pb2, float* __restrict__ gate) {
  __shared__ float pooled[2 * D_DIM];
  __shared__ float hsh[2][64];
  int t = threadIdx.x;
  for (int idx = t; idx < 2 * D_DIM; idx += 128) {
    int b = idx >> 10, k = idx & 1023;
    float s = 0.f;
#pragma unroll
    for (int c = 0; c < 8; ++c) s += partial[(b * 8 + c) * D_DIM + k];
    pooled[idx] = s * (1.0f / 2048.0f);
  }
  __syncthreads();
  int b = t >> 6, j = t & 63;
  float acc = pb1[j];
  for (int k = 0; k < D_DIM; ++k) acc += pooled[b * D_DIM + k] * pW1[k * 64 + j];
  acc = (acc - mean[j]) * rsqrtf(var[j] + 1e-12f) * gamma[j] + beta[j];
  hsh[b][j] = fmaxf(acc, 0.f);
  __syncthreads();
  if (t < 32) {
    int bb = t >> 4, hh = t & 15;
    float lg = pb2[hh];
#pragma unroll
    for (int jj = 0; jj < 64; ++jj) lg += hsh[bb][jj] * pW2[jj * NH + hh];
    gate[bb * NH + hh] = (lg >= 0.f) ? 1.f : 0.f;
  }
}

// ---------------- projection GEMM (bt pattern) ----------------
#define BM 128
#define BN 128
#define BK 32
#define LDK 40

__global__ __launch_bounds__(256) void proj_gemm(const unsigned short* __restrict__ A,
                                                 const unsigned short* __restrict__ BT,
                                                 const float* __restrict__ bias,
                                                 unsigned short* __restrict__ Cout,
                                                 int mode) {
  __shared__ __align__(16) unsigned short As[BM][LDK];
  __shared__ __align__(16) unsigned short Bs[BN][LDK];
  int m0 = blockIdx.x * BM;
  int n0 = blockIdx.y * BN;
  int tid = threadIdx.x;
  int wave = tid >> 6, lane = tid & 63;
  int l15 = lane & 15, lhi = lane >> 4;
  int wm = (wave >> 1) * 64, wn = (wave & 1) * 64;
  f32x4 acc[4][4] = {};

  for (int k0 = 0; k0 < D_DIM; k0 += BK) {
#pragma unroll
    for (int i = 0; i < 2; ++i) {
      int idx = (tid + i * 256) * 8;
      int r = idx >> 5;
      int c = idx & 31;
      *(u16x8*)&As[r][c] = *(const u16x8*)(A + (size_t)(m0 + r) * D_DIM + k0 + c);
      *(u16x8*)&Bs[r][c] = *(const u16x8*)(BT + (size_t)(n0 + r) * D_DIM + k0 + c);
    }
    __syncthreads();
    s16x8 af[4], bf[4];
#pragma unroll
    for (int mi = 0; mi < 4; ++mi)
      af[mi] = *(const s16x8*)&As[wm + mi * 16 + l15][lhi * 8];
#pragma unroll
    for (int ni = 0; ni < 4; ++ni)
      bf[ni] = *(const s16x8*)&Bs[wn + ni * 16 + l15][lhi * 8];
#pragma unroll
    for (int mi = 0; mi < 4; ++mi)
#pragma unroll
      for (int ni = 0; ni < 4; ++ni)
        acc[mi][ni] = mfma_bf16(af[mi], bf[ni], acc[mi][ni]);
    __syncthreads();
  }

#pragma unroll
  for (int mi = 0; mi < 4; ++mi)
#pragma unroll
    for (int ni = 0; ni < 4; ++ni)
#pragma unroll
      for (int r = 0; r < 4; ++r) {
        int row = m0 + wm + mi * 16 + lhi * 4 + r;
        int col = n0 + wn + ni * 16 + l15;
        float v = acc[mi][ni][r] + ((mode == 1) ? bias[row] : bias[col]);
        unsigned short bv = f32_to_bf16(v);
        if (mode == 0) {
          int b = row >> 11, s = row & 2047;
          int h = col >> 6, d = col & 63;
          Cout[((size_t)(b * NH + h) * S_LEN + s) * HD + d] = bv;
        } else {
          int h = row >> 6, d = row & 63;
          int b = col >> 11, s = col & 2047;
          Cout[((size_t)(b * NH + h) * HD + d) * S_LEN + s] = bv;
        }
      }
}

// ---------------- flash attention: LDS-staged double-buffered K/V (T3 2-phase) ----
// grid: 1024 blocks, idx -> bh = idx & 31, qc = idx >> 5. 4 waves, 16 q-rows/wave.
// Per tile: fire global_load_lds DMA for tile t+1 into buf^1, compute tile t from
// buf (ds_read K -> QK -> softmax -> P -> PV), one __syncthreads (drains vmcnt).
// LDS tiles are XOR-swizzled (byte ^= (row&7)<<4) via pre-swizzled GLOBAL source
// (global_load_lds writes linearly) + swizzled ds_read — bank conflicts ~2-way.
__global__ __launch_bounds__(256) void attn_kernel(
    const unsigned short* __restrict__ Q, const unsigned short* __restrict__ K,
    const unsigned short* __restrict__ Vt, const float* __restrict__ mask,
    const float* __restrict__ gate, float* __restrict__ Out) {
  __shared__ __align__(16) unsigned short Ks[2][64 * 64];   // [key][d], swizzled
  __shared__ __align__(16) unsigned short Vs[2][64 * 64];   // [d][key], swizzled
  __shared__ __align__(16) unsigned short p_lds[4][2][16][72];
  __shared__ __align__(16) float mask_lds[S_LEN];

  int idx = blockIdx.x;
  int bh = idx & 31;
  int qc = idx >> 5;
  int b = bh >> 4, h = bh & 15;
  int tid = threadIdx.x;
  int wave = tid >> 6, lane = tid & 63;
  int l15 = lane & 15, lhi = lane >> 4;
  int q0 = qc * 64 + wave * 16;
  int qrow = q0 + l15;

  float g = gate[bh];
  if (g == 0.f) {  // gated-off head: exactly zero (block-uniform exit, pre-barrier)
    float4 z = {0.f, 0.f, 0.f, 0.f};
#pragma unroll
    for (int dd = 0; dd < 4; ++dd)
      *(float4*)(Out + ((size_t)b * S_LEN + qrow) * D_DIM + h * HD + lhi * 16 + dd * 4) = z;
    return;
  }

  const unsigned short* Qp = Q + (size_t)bh * S_LEN * HD;
  const unsigned short* Kp = K + (size_t)bh * S_LEN * HD;
  const unsigned short* Vp = Vt + (size_t)bh * HD * S_LEN;

  // staging geometry: per lane, two 16B DMA chunks covering this wave's 2KB slice
  int o0 = wave * 2048 + lane * 16;  // byte offset within the 8KB tile

#define STAGE(BUFI, KTV)                                                          \
  {                                                                               \
    _Pragma("unroll") for (int j = 0; j < 2; ++j) {                               \
      int oo = o0 + j * 1024;                                                     \
      int row = oo >> 7;                                                          \
      int e = ((oo & 127) ^ ((row & 7) << 4)) >> 1;                               \
      __builtin_amdgcn_global_load_lds(                                           \
          (gas_ptr)(Kp + (size_t)((KTV) + row) * HD + e),                         \
          (las_ptr)(&Ks[BUFI][(wave * 2048 + j * 1024) >> 1]), 16, 0, 0);         \
      __builtin_amdgcn_global_load_lds(                                           \
          (gas_ptr)(Vp + (size_t)row * S_LEN + (KTV) + e),                        \
          (las_ptr)(&Vs[BUFI][(wave * 2048 + j * 1024) >> 1]), 16, 0, 0);         \
    }                                                                             \
  }

  // prologue: stage tile 0 into buf 0; mask row -> LDS; Q fragments -> regs
  STAGE(0, 0);
  for (int i = tid * 4; i < S_LEN; i += 256 * 4)
    *(float4*)&mask_lds[i] = *(const float4*)(mask + (size_t)b * S_LEN + i);

  s16x8 q_frag[2];
#pragma unroll
  for (int ks = 0; ks < 2; ++ks)
    q_frag[ks] = *(const s16x8*)(Qp + (size_t)qrow * HD + ks * 32 + lhi * 8);

  f32x4 o_acc[4] = {};
  float m_run = -1e30f, s_run = 0.f;
  const float scl = 0.125f;  // 1/sqrt(64)

  __syncthreads();  // tile 0 staged & visible

  for (int kt = 0; kt < S_LEN; kt += 64) {
    int buf = (kt >> 6) & 1;
    int ktn = (kt + 64) & (S_LEN - 1);  // last iter wraps harmlessly
    STAGE(buf ^ 1, ktn);                // fire next-tile DMA before compute

    // ---- QK^T from LDS (swizzled reads): sc[nf][r] = S[q=l15][key=nf*16+lhi*4+r]
    f32x4 sc[4] = {};
    __builtin_amdgcn_s_setprio(1);
#pragma unroll
    for (int ks = 0; ks < 2; ++ks)
#pragma unroll
      for (int nf = 0; nf < 4; ++nf) {
        int row = nf * 16 + l15;
        int ofs = (row * 128 + ks * 64 + lhi * 16) ^ ((row & 7) << 4);
        s16x8 af = *(const s16x8*)((const char*)&Ks[buf][0] + ofs);
        sc[nf] = mfma_bf16(af, q_frag[ks], sc[nf]);
      }
    __builtin_amdgcn_s_setprio(0);

    // ---- scale + mask + tree max (lane-local row stats)
    float mnf[4];
#pragma unroll
    for (int nf = 0; nf < 4; ++nf) {
      float4 mv = *(const float4*)&mask_lds[kt + nf * 16 + lhi * 4];
#pragma unroll
      for (int r = 0; r < 4; ++r) sc[nf][r] = sc[nf][r] * scl + ((const float*)&mv)[r];
      mnf[nf] = fmaxf(fmaxf(sc[nf][0], sc[nf][1]), fmaxf(sc[nf][2], sc[nf][3]));
    }
    float mx = fmaxf(fmaxf(mnf[0], mnf[1]), fmaxf(mnf[2], mnf[3]));
    mx = fmaxf(mx, __shfl_xor(mx, 16, 64));
    mx = fmaxf(mx, __shfl_xor(mx, 32, 64));

    float m_new = fmaxf(m_run, mx);
    float corr = __expf(m_run - m_new);
    m_run = m_new;

    float psnf[4];
#pragma unroll
    for (int nf = 0; nf < 4; ++nf) {
#pragma unroll
      for (int r = 0; r < 4; ++r) sc[nf][r] = __expf(sc[nf][r] - m_new);
      psnf[nf] = (sc[nf][0] + sc[nf][1]) + (sc[nf][2] + sc[nf][3]);
    }
    float ps = (psnf[0] + psnf[1]) + (psnf[2] + psnf[3]);
    ps += __shfl_xor(ps, 16, 64);
    ps += __shfl_xor(ps, 32, 64);
    s_run = s_run * corr + ps;

#pragma unroll
    for (int df = 0; df < 4; ++df)
#pragma unroll
      for (int r = 0; r < 4; ++r) o_acc[df][r] *= corr;

    // ---- P -> per-wave LDS (parity dbuf), re-layout for PV A-operand
#pragma unroll
    for (int nf = 0; nf < 4; ++nf) {
      unsigned int lo = (unsigned int)f32_to_bf16(sc[nf][0]) |
                        ((unsigned int)f32_to_bf16(sc[nf][1]) << 16);
      unsigned int hi = (unsigned int)f32_to_bf16(sc[nf][2]) |
                        ((unsigned int)f32_to_bf16(sc[nf][3]) << 16);
      uint2 pk = {lo, hi};
      *(uint2*)&p_lds[wave][buf][l15][nf * 16 + lhi * 4] = pk;
    }

    // ---- O^T += V^T · P^T from LDS (swizzled V reads)
    __builtin_amdgcn_s_setprio(1);
#pragma unroll
    for (int ks = 0; ks < 2; ++ks) {
      s16x8 pf = *(const s16x8*)&p_lds[wave][buf][l15][ks * 32 + lhi * 8];
#pragma unroll
      for (int df = 0; df < 4; ++df) {
        int row = df * 16 + l15;
        int ofs = (row * 128 + ks * 64 + lhi * 16) ^ ((row & 7) << 4);
        s16x8 vf = *(const s16x8*)((const char*)&Vs[buf][0] + ofs);
        o_acc[df] = mfma_bf16(vf, pf, o_acc[df]);
      }
    }
    __builtin_amdgcn_s_setprio(0);

    __syncthreads();  // drains our DMA (vmcnt 0) + WAR fence on buf for next iter
  }
#undef STAGE

  float inv = g / s_run;
#pragma unroll
  for (int df = 0; df < 4; ++df) {
    float4 ov;
    ov.x = o_acc[df][0] * inv;
    ov.y = o_acc[df][1] * inv;
    ov.z = o_acc[df][2] * inv;
    ov.w = o_acc[df][3] * inv;
    *(float4*)(Out + ((size_t)b * S_LEN + qrow) * D_DIM + h * HD + df * 16 + lhi * 4) = ov;
  }
}

// ---------------- launch ----------------

extern "C" void kernel_launch(void* const* d_in, const int* in_sizes, int n_in,
                              void* d_out, int out_size, void* d_ws, size_t ws_size,
                              hipStream_t stream) {
  (void)in_sizes; (void)n_in; (void)out_size; (void)ws_size;
  const float* hs   = (const float*)d_in[0];
  const float* mask = (const float*)d_in[1];
  const float* Wq   = (const float*)d_in[2];
  const float* bq   = (const float*)d_in[3];
  const float* Wk   = (const float*)d_in[4];
  const float* bk   = (const float*)d_in[5];
  const float* Wv   = (const float*)d_in[6];
  const float* bv   = (const float*)d_in[7];
  const float* pW1  = (const float*)d_in[8];
  const float* pb1  = (const float*)d_in[9];
  const float* gam  = (const float*)d_in[10];
  const float* bet  = (const float*)d_in[11];
  const float* mea  = (const float*)d_in[12];
  const float* var  = (const float*)d_in[13];
  const float* pW2  = (const float*)d_in[14];
  const float* pb2  = (const float*)d_in[15];
  float* out = (float*)d_out;

  const size_t MB = 1u << 20;
  char* ws = (char*)d_ws;
  unsigned short* hsb = (unsigned short*)(ws);            // 8 MB [4096][1024]
  unsigned short* wTq = (unsigned short*)(ws + 8 * MB);   // 2 MB
  unsigned short* wTk = (unsigned short*)(ws + 10 * MB);  // 2 MB
  unsigned short* wTv = (unsigned short*)(ws + 12 * MB);  // 2 MB
  unsigned short* Qb  = (unsigned short*)(ws + 14 * MB);  // 8 MB [32][2048][64]
  unsigned short* Kb  = (unsigned short*)(ws + 22 * MB);  // 8 MB [32][2048][64]
  unsigned short* Vtb = (unsigned short*)(ws + 30 * MB);  // 8 MB [32][64][2048]
  float* partial = (float*)(ws + 38 * MB);                // 64 KB [2][8][1024]
  float* gateb   = (float*)(ws + 38 * MB + 65536);        // 128 B [32]

  cvt_hs_bf16<<<2048, 256, 0, stream>>>(hs, hsb);
  transpose_w<<<dim3(32, 32), 256, 0, stream>>>(Wq, wTq);
  transpose_w<<<dim3(32, 32), 256, 0, stream>>>(Wk, wTk);
  transpose_w<<<dim3(32, 32), 256, 0, stream>>>(Wv, wTv);
  pool_partial<<<64, 256, 0, stream>>>(hs, partial);
  gate_kernel<<<1, 128, 0, stream>>>(partial, pW1, pb1, gam, bet, mea, var, pW2, pb2, gateb);

  proj_gemm<<<dim3(32, 8), 256, 0, stream>>>(hsb, wTq, bq, Qb, 0);
  proj_gemm<<<dim3(32, 8), 256, 0, stream>>>(hsb, wTk, bk, Kb, 0);
  proj_gemm<<<dim3(8, 32), 256, 0, stream>>>(wTv, hsb, bv, Vtb, 1);

  attn_kernel<<<1024, 256, 0, stream>>>(Qb, Kb, Vtb, mask, gateb, out);
}

// Round 5
// 174.852 us; speedup vs baseline: 2.8009x; 1.2698x over previous
//
#include <hip/hip_runtime.h>

#define S_LEN 2048
#define D_DIM 1024
#define NH 16
#define HD 64
#define BATCH 2

using s16x8 = __attribute__((ext_vector_type(8))) short;
using u16x8 = __attribute__((ext_vector_type(8))) unsigned short;
using f32x4 = __attribute__((ext_vector_type(4))) float;
using bf16x8v = __attribute__((ext_vector_type(8))) __bf16;

typedef const __attribute__((address_space(1))) unsigned int* gas_ptr;
typedef __attribute__((address_space(3))) unsigned int* las_ptr;

__device__ __forceinline__ unsigned short f32_to_bf16(float f) {
  unsigned int u = __float_as_uint(f);
  u += 0x7FFFu + ((u >> 16) & 1u);
  return (unsigned short)(u >> 16);
}

__device__ __forceinline__ f32x4 mfma_bf16(s16x8 a, s16x8 b, f32x4 c) {
  return __builtin_amdgcn_mfma_f32_16x16x32_bf16(
      __builtin_bit_cast(bf16x8v, a), __builtin_bit_cast(bf16x8v, b), c, 0, 0, 0);
}

// ---------------- conversion kernels ----------------

__global__ __launch_bounds__(256) void cvt_hs_bf16(const float* __restrict__ in,
                                                   unsigned short* __restrict__ out) {
  int i = (blockIdx.x * 256 + threadIdx.x) * 8;
  float4 v0 = *(const float4*)(in + i);
  float4 v1 = *(const float4*)(in + i + 4);
  u16x8 o;
  o[0] = f32_to_bf16(v0.x); o[1] = f32_to_bf16(v0.y);
  o[2] = f32_to_bf16(v0.z); o[3] = f32_to_bf16(v0.w);
  o[4] = f32_to_bf16(v1.x); o[5] = f32_to_bf16(v1.y);
  o[6] = f32_to_bf16(v1.z); o[7] = f32_to_bf16(v1.w);
  *(u16x8*)(out + i) = o;
}

// WT[n][k] = W[k][n], f32 -> bf16
__global__ __launch_bounds__(256) void transpose_w(const float* __restrict__ W,
                                                   unsigned short* __restrict__ WT) {
  __shared__ float tile[32][33];
  int tx = threadIdx.x & 31;
  int ty = threadIdx.x >> 5;  // 0..7
  int c0 = blockIdx.x * 32;   // n range
  int r0 = blockIdx.y * 32;   // k range
#pragma unroll
  for (int i = 0; i < 4; ++i)
    tile[ty + i * 8][tx] = W[(r0 + ty + i * 8) * D_DIM + c0 + tx];
  __syncthreads();
#pragma unroll
  for (int i = 0; i < 4; ++i)
    WT[(c0 + ty + i * 8) * D_DIM + r0 + tx] = f32_to_bf16(tile[tx][ty + i * 8]);
}

// ---------------- pooling + gate ----------------

__global__ __launch_bounds__(256) void pool_partial(const float* __restrict__ hs,
                                                    float* __restrict__ partial) {
  int bid = blockIdx.x;  // 64 = 2 * 8 * 4
  int b = bid & 1;
  int chunk = (bid >> 1) & 7;
  int dq = bid >> 4;  // 0..3
  int d = dq * 256 + threadIdx.x;
  const float* p = hs + ((size_t)b * S_LEN + chunk * 256) * D_DIM + d;
  float s = 0.f;
  for (int i = 0; i < 256; ++i) s += p[(size_t)i * D_DIM];
  partial[(b * 8 + chunk) * D_DIM + d] = s;
}

__global__ __launch_bounds__(256) void gate_kernel(
    const float* __restrict__ partial, const float* __restrict__ pW1,
    const float* __restrict__ pb1, const float* __restrict__ gamma,
    const float* __restrict__ beta, const float* __restrict__ mean,
    const float* __restrict__ var, const float* __restrict__ pW2,
    const float* __restrict__ pb2, float* __restrict__ gate) {
  __shared__ float pooled[2 * D_DIM];
  __shared__ float hsh[2][64];
  int t = threadIdx.x;
  for (int idx = t; idx < 2 * D_DIM; idx += 256) {
    int b = idx >> 10, k = idx & 1023;
    float s = 0.f;
#pragma unroll
    for (int c = 0; c < 8; ++c) s += partial[(b * 8 + c) * D_DIM + k];
    pooled[idx] = s * (1.0f / 2048.0f);
  }
  __syncthreads();
  // 2 threads per (b,j): split k-range, shfl combine
  int b = t >> 7, jj = (t >> 1) & 63, half = t & 1;
  float acc = 0.f;
  for (int k = half * 512; k < half * 512 + 512; ++k)
    acc += pooled[b * D_DIM + k] * pW1[k * 64 + jj];
  acc += __shfl_xor(acc, 1, 64);
  if (half == 0) {
    acc += pb1[jj];
    acc = (acc - mean[jj]) * rsqrtf(var[jj] + 1e-12f) * gamma[jj] + beta[jj];
    hsh[b][jj] = fmaxf(acc, 0.f);
  }
  __syncthreads();
  if (t < 32) {
    int bb = t >> 4, hh = t & 15;
    float lg = pb2[hh];
#pragma unroll
    for (int kk = 0; kk < 64; ++kk) lg += hsh[bb][kk] * pW2[kk * NH + hh];
    gate[bb * NH + hh] = (lg >= 0.f) ? 1.f : 0.f;
  }
}

// ---------------- projection GEMM (m97 structure: global_load_lds staging) -------
// C[m][n] = sum_k A[m][k]*BT[n][k] + bias. 128x128 tile, BK=32, 4 waves (2x2 of
// 64x64), 16 MFMA/iter, 16B global_load_lds staging, linear LDS.
// mode 0 (fused QK): A=hs_bf16 (M=4096), BT=wTq||wTk (N=2048);
//   col<1024 -> Q (bias0/out0), else K (bias1/out1); out [b,h,s,d] bf16.
// mode 1 (V^T): A=wTv (M=1024), BT=hs_bf16 (N=4096); out [b,h,d,s] bf16.
__global__ __launch_bounds__(256) void proj_gemm2(
    const unsigned short* __restrict__ A, const unsigned short* __restrict__ BT,
    const float* __restrict__ bias0, const float* __restrict__ bias1,
    unsigned short* __restrict__ out0, unsigned short* __restrict__ out1,
    int mode) {
  __shared__ __align__(16) unsigned short As[128 * 32];
  __shared__ __align__(16) unsigned short Bs[128 * 32];
  int m0 = blockIdx.x * 128, n0 = blockIdx.y * 128;
  int tid = threadIdx.x, wave = tid >> 6, lane = tid & 63;
  int l15 = lane & 15, lhi = lane >> 4;
  int wm = (wave >> 1) * 64, wn = (wave & 1) * 64;
  int srow = tid >> 2;        // 0..63: row within the 64-row half per round
  int scol = (tid & 3) * 8;   // element col 0/8/16/24
  f32x4 acc[4][4] = {};

  for (int k0 = 0; k0 < D_DIM; k0 += 32) {
#pragma unroll
    for (int j = 0; j < 2; ++j) {
      __builtin_amdgcn_global_load_lds(
          (gas_ptr)(A + (size_t)(m0 + j * 64 + srow) * D_DIM + k0 + scol),
          (las_ptr)((char*)As + j * 4096 + wave * 1024), 16, 0, 0);
      __builtin_amdgcn_global_load_lds(
          (gas_ptr)(BT + (size_t)(n0 + j * 64 + srow) * D_DIM + k0 + scol),
          (las_ptr)((char*)Bs + j * 4096 + wave * 1024), 16, 0, 0);
    }
    __syncthreads();
    s16x8 af[4], bf[4];
#pragma unroll
    for (int mi = 0; mi < 4; ++mi)
      af[mi] = *(const s16x8*)((const char*)As + (wm + mi * 16 + l15) * 64 + lhi * 16);
#pragma unroll
    for (int ni = 0; ni < 4; ++ni)
      bf[ni] = *(const s16x8*)((const char*)Bs + (wn + ni * 16 + l15) * 64 + lhi * 16);
#pragma unroll
    for (int mi = 0; mi < 4; ++mi)
#pragma unroll
      for (int ni = 0; ni < 4; ++ni)
        acc[mi][ni] = mfma_bf16(af[mi], bf[ni], acc[mi][ni]);
    __syncthreads();
  }

#pragma unroll
  for (int mi = 0; mi < 4; ++mi)
#pragma unroll
    for (int ni = 0; ni < 4; ++ni)
#pragma unroll
      for (int r = 0; r < 4; ++r) {
        int row = m0 + wm + mi * 16 + lhi * 4 + r;
        int col = n0 + wn + ni * 16 + l15;
        if (mode == 0) {
          const float* bb = (col < 1024) ? bias0 : bias1;
          unsigned short* dst = (col < 1024) ? out0 : out1;
          int c = col & 1023;
          unsigned short bv = f32_to_bf16(acc[mi][ni][r] + bb[c]);
          int b = row >> 11, s = row & 2047;
          int h = c >> 6, d = c & 63;
          dst[((size_t)(b * NH + h) * S_LEN + s) * HD + d] = bv;
        } else {
          unsigned short bv = f32_to_bf16(acc[mi][ni][r] + bias0[row]);
          int h = row >> 6, d = row & 63;
          int b = col >> 11, s = col & 2047;
          out0[((size_t)(b * NH + h) * HD + d) * S_LEN + s] = bv;
        }
      }
}

// ---------------- flash attention: LDS-staged double-buffered K/V ----------------
// grid: 1024 blocks, bh = idx>>5, qc = idx&31 (consecutive blocks share head ->
// a CU's residency slots get DIFFERENT heads -> gate load-balance). 4 waves,
// 16 q-rows/wave. Per tile: fire DMA for t+1, compute t, one barrier.
// K/V LDS XOR-swizzled via pre-swizzled global source. Defer-max (THR=8).
__global__ __launch_bounds__(256) void attn_kernel(
    const unsigned short* __restrict__ Q, const unsigned short* __restrict__ K,
    const unsigned short* __restrict__ Vt, const float* __restrict__ mask,
    const float* __restrict__ gate, float* __restrict__ Out) {
  __shared__ __align__(16) unsigned short Ks[2][64 * 64];   // [key][d], swizzled
  __shared__ __align__(16) unsigned short Vs[2][64 * 64];   // [d][key], swizzled
  __shared__ __align__(16) unsigned short p_lds[4][16][72];

  int idx = blockIdx.x;
  int bh = idx >> 5;
  int qc = idx & 31;
  int b = bh >> 4, h = bh & 15;
  int tid = threadIdx.x;
  int wave = tid >> 6, lane = tid & 63;
  int l15 = lane & 15, lhi = lane >> 4;
  int q0 = qc * 64 + wave * 16;
  int qrow = q0 + l15;

  float g = gate[bh];
  if (g == 0.f) {  // gated-off head: exactly zero (block-uniform exit, pre-barrier)
    float4 z = {0.f, 0.f, 0.f, 0.f};
#pragma unroll
    for (int dd = 0; dd < 4; ++dd)
      *(float4*)(Out + ((size_t)b * S_LEN + qrow) * D_DIM + h * HD + lhi * 16 + dd * 4) = z;
    return;
  }

  const unsigned short* Qp = Q + (size_t)bh * S_LEN * HD;
  const unsigned short* Kp = K + (size_t)bh * S_LEN * HD;
  const unsigned short* Vp = Vt + (size_t)bh * HD * S_LEN;
  const float* maskp = mask + (size_t)b * S_LEN;

  // staging geometry: per lane, two 16B DMA chunks covering this wave's 2KB slice
  int o0 = wave * 2048 + lane * 16;  // byte offset within the 8KB tile

#define STAGE(BUFI, KTV)                                                          \
  {                                                                               \
    _Pragma("unroll") for (int j = 0; j < 2; ++j) {                               \
      int oo = o0 + j * 1024;                                                     \
      int row = oo >> 7;                                                          \
      int e = ((oo & 127) ^ ((row & 7) << 4)) >> 1;                               \
      __builtin_amdgcn_global_load_lds(                                           \
          (gas_ptr)(Kp + (size_t)((KTV) + row) * HD + e),                         \
          (las_ptr)(&Ks[BUFI][(wave * 2048 + j * 1024) >> 1]), 16, 0, 0);         \
      __builtin_amdgcn_global_load_lds(                                           \
          (gas_ptr)(Vp + (size_t)row * S_LEN + (KTV) + e),                        \
          (las_ptr)(&Vs[BUFI][(wave * 2048 + j * 1024) >> 1]), 16, 0, 0);         \
    }                                                                             \
  }

  // prologue: stage tile 0 into buf 0; Q fragments -> regs
  STAGE(0, 0);
  s16x8 q_frag[2];
#pragma unroll
  for (int ks = 0; ks < 2; ++ks)
    q_frag[ks] = *(const s16x8*)(Qp + (size_t)qrow * HD + ks * 32 + lhi * 8);

  f32x4 o_acc[4] = {};
  float m_run = -1e30f, s_run = 0.f;
  const float scl = 0.125f;  // 1/sqrt(64)

  __syncthreads();  // tile 0 staged & visible

  for (int kt = 0; kt < S_LEN; kt += 64) {
    int buf = (kt >> 6) & 1;
    int ktn = (kt + 64) & (S_LEN - 1);  // last iter wraps harmlessly
    STAGE(buf ^ 1, ktn);                // fire next-tile DMA before compute

    // mask slice (L2-hot, issued before MFMA phase -> latency hidden)
    float4 mv[4];
#pragma unroll
    for (int nf = 0; nf < 4; ++nf)
      mv[nf] = *(const float4*)(maskp + kt + nf * 16 + lhi * 4);

    // ---- QK^T from LDS (swizzled reads): sc[nf][r] = S[q=l15][key=nf*16+lhi*4+r]
    f32x4 sc[4] = {};
    __builtin_amdgcn_s_setprio(1);
#pragma unroll
    for (int ks = 0; ks < 2; ++ks)
#pragma unroll
      for (int nf = 0; nf < 4; ++nf) {
        int row = nf * 16 + l15;
        int ofs = (row * 128 + ks * 64 + lhi * 16) ^ ((row & 7) << 4);
        s16x8 af = *(const s16x8*)((const char*)&Ks[buf][0] + ofs);
        sc[nf] = mfma_bf16(af, q_frag[ks], sc[nf]);
      }
    __builtin_amdgcn_s_setprio(0);

    // ---- scale + mask + tree max (lane-local row stats)
    float mnf[4];
#pragma unroll
    for (int nf = 0; nf < 4; ++nf) {
#pragma unroll
      for (int r = 0; r < 4; ++r) sc[nf][r] = sc[nf][r] * scl + ((const float*)&mv[nf])[r];
      mnf[nf] = fmaxf(fmaxf(sc[nf][0], sc[nf][1]), fmaxf(sc[nf][2], sc[nf][3]));
    }
    float pmax = fmaxf(fmaxf(mnf[0], mnf[1]), fmaxf(mnf[2], mnf[3]));
    pmax = fmaxf(pmax, __shfl_xor(pmax, 16, 64));
    pmax = fmaxf(pmax, __shfl_xor(pmax, 32, 64));

    // defer-max: skip rescale while tile max stays within THR of running max
    if (!__all(pmax <= m_run + 8.f)) {
      float m_new = fmaxf(m_run, pmax);
      float corr = __expf(m_run - m_new);
      m_run = m_new;
      s_run *= corr;
#pragma unroll
      for (int df = 0; df < 4; ++df)
#pragma unroll
        for (int r = 0; r < 4; ++r) o_acc[df][r] *= corr;
    }

    float psnf[4];
#pragma unroll
    for (int nf = 0; nf < 4; ++nf) {
#pragma unroll
      for (int r = 0; r < 4; ++r) sc[nf][r] = __expf(sc[nf][r] - m_run);
      psnf[nf] = (sc[nf][0] + sc[nf][1]) + (sc[nf][2] + sc[nf][3]);
    }
    float ps = (psnf[0] + psnf[1]) + (psnf[2] + psnf[3]);
    ps += __shfl_xor(ps, 16, 64);
    ps += __shfl_xor(ps, 32, 64);
    s_run += ps;

    // ---- P -> per-wave LDS slice (barrier-ordered; re-layout for PV A-operand)
#pragma unroll
    for (int nf = 0; nf < 4; ++nf) {
      unsigned int lo = (unsigned int)f32_to_bf16(sc[nf][0]) |
                        ((unsigned int)f32_to_bf16(sc[nf][1]) << 16);
      unsigned int hi = (unsigned int)f32_to_bf16(sc[nf][2]) |
                        ((unsigned int)f32_to_bf16(sc[nf][3]) << 16);
      uint2 pk = {lo, hi};
      *(uint2*)&p_lds[wave][l15][nf * 16 + lhi * 4] = pk;
    }

    // ---- O^T += V^T · P^T from LDS (swizzled V reads)
    __builtin_amdgcn_s_setprio(1);
#pragma unroll
    for (int ks = 0; ks < 2; ++ks) {
      s16x8 pf = *(const s16x8*)&p_lds[wave][l15][ks * 32 + lhi * 8];
#pragma unroll
      for (int df = 0; df < 4; ++df) {
        int row = df * 16 + l15;
        int ofs = (row * 128 + ks * 64 + lhi * 16) ^ ((row & 7) << 4);
        s16x8 vf = *(const s16x8*)((const char*)&Vs[buf][0] + ofs);
        o_acc[df] = mfma_bf16(vf, pf, o_acc[df]);
      }
    }
    __builtin_amdgcn_s_setprio(0);

    __syncthreads();  // drains our DMA (vmcnt 0) + WAR fence on buf/p_lds
  }
#undef STAGE

  float inv = g / s_run;
#pragma unroll
  for (int df = 0; df < 4; ++df) {
    float4 ov;
    ov.x = o_acc[df][0] * inv;
    ov.y = o_acc[df][1] * inv;
    ov.z = o_acc[df][2] * inv;
    ov.w = o_acc[df][3] * inv;
    *(float4*)(Out + ((size_t)b * S_LEN + qrow) * D_DIM + h * HD + df * 16 + lhi * 4) = ov;
  }
}

// ---------------- launch ----------------

extern "C" void kernel_launch(void* const* d_in, const int* in_sizes, int n_in,
                              void* d_out, int out_size, void* d_ws, size_t ws_size,
                              hipStream_t stream) {
  (void)in_sizes; (void)n_in; (void)out_size; (void)ws_size;
  const float* hs   = (const float*)d_in[0];
  const float* mask = (const float*)d_in[1];
  const float* Wq   = (const float*)d_in[2];
  const float* bq   = (const float*)d_in[3];
  const float* Wk   = (const float*)d_in[4];
  const float* bk   = (const float*)d_in[5];
  const float* Wv   = (const float*)d_in[6];
  const float* bv   = (const float*)d_in[7];
  const float* pW1  = (const float*)d_in[8];
  const float* pb1  = (const float*)d_in[9];
  const float* gam  = (const float*)d_in[10];
  const float* bet  = (const float*)d_in[11];
  const float* mea  = (const float*)d_in[12];
  const float* var  = (const float*)d_in[13];
  const float* pW2  = (const float*)d_in[14];
  const float* pb2  = (const float*)d_in[15];
  float* out = (float*)d_out;

  const size_t MB = 1u << 20;
  char* ws = (char*)d_ws;
  unsigned short* hsb = (unsigned short*)(ws);            // 8 MB [4096][1024]
  unsigned short* wTq = (unsigned short*)(ws + 8 * MB);   // 2 MB (wTk must follow!)
  unsigned short* wTk = (unsigned short*)(ws + 10 * MB);  // 2 MB
  unsigned short* wTv = (unsigned short*)(ws + 12 * MB);  // 2 MB
  unsigned short* Qb  = (unsigned short*)(ws + 14 * MB);  // 8 MB [32][2048][64]
  unsigned short* Kb  = (unsigned short*)(ws + 22 * MB);  // 8 MB [32][2048][64]
  unsigned short* Vtb = (unsigned short*)(ws + 30 * MB);  // 8 MB [32][64][2048]
  float* partial = (float*)(ws + 38 * MB);                // 64 KB [2][8][1024]
  float* gateb   = (float*)(ws + 38 * MB + 65536);        // 128 B [32]

  cvt_hs_bf16<<<2048, 256, 0, stream>>>(hs, hsb);
  transpose_w<<<dim3(32, 32), 256, 0, stream>>>(Wq, wTq);
  transpose_w<<<dim3(32, 32), 256, 0, stream>>>(Wk, wTk);
  transpose_w<<<dim3(32, 32), 256, 0, stream>>>(Wv, wTv);
  pool_partial<<<64, 256, 0, stream>>>(hs, partial);
  gate_kernel<<<1, 256, 0, stream>>>(partial, pW1, pb1, gam, bet, mea, var, pW2, pb2, gateb);

  // fused Q+K projection: N = 2048 over [wTq | wTk] (adjacent in ws)
  proj_gemm2<<<dim3(32, 16), 256, 0, stream>>>(hsb, wTq, bq, bk, Qb, Kb, 0);
  // V^T projection
  proj_gemm2<<<dim3(8, 32), 256, 0, stream>>>(wTv, hsb, bv, nullptr, Vtb, nullptr, 1);

  attn_kernel<<<1024, 256, 0, stream>>>(Qb, Kb, Vtb, mask, gateb, out);
}